// Round 10
// baseline (217.738 us; speedup 1.0000x reference)
//
#include <hip/hip_runtime.h>
#include <stdint.h>

// ---------------------------------------------------------------------------
// MHSA: B=8, N=1024, C=768, H=12, HD=64, SCALE=0.125
// Inputs/outputs fp32; internal compute bf16 MFMA with fp32 accumulation.
// Round 10: QKV gemm retiled 128x128 -> 64x128 (2304 blocks = 9/CU, 24 KB
// LDS = 6 resident/CU) to hide the per-iter barrier drain cross-block.
// Attn + out-proj unchanged from round 9.
// ---------------------------------------------------------------------------

typedef __attribute__((ext_vector_type(8))) __bf16 bf16x8;
typedef __attribute__((ext_vector_type(4))) float f32x4;

__device__ __forceinline__ uint16_t f2bf(float f) {
    union { float f; unsigned u; } c; c.f = f;
    unsigned x = c.u;
    unsigned r = (x + 0x7FFFu + ((x >> 16) & 1u)) >> 16;  // round-nearest-even
    return (uint16_t)r;
}

__device__ __forceinline__ void gload_lds16(const uint16_t* g, uint16_t* l) {
    __builtin_amdgcn_global_load_lds(
        (const __attribute__((address_space(1))) unsigned int*)g,
        (__attribute__((address_space(3))) unsigned int*)l, 16, 0, 0);
}

// ---------------------------------------------------------------------------
// fp32 -> bf16 convert, 8 elements/thread
// ---------------------------------------------------------------------------
__global__ __launch_bounds__(256) void cvt_f32_bf16(
    const float* __restrict__ src, uint16_t* __restrict__ dst, int n) {
    int i = (blockIdx.x * 256 + threadIdx.x) * 8;
    if (i + 8 > n) return;
    float4 a = *(const float4*)(src + i);
    float4 b = *(const float4*)(src + i + 4);
    union { uint16_t u[8]; uint4 v; } o;
    o.u[0] = f2bf(a.x); o.u[1] = f2bf(a.y); o.u[2] = f2bf(a.z); o.u[3] = f2bf(a.w);
    o.u[4] = f2bf(b.x); o.u[5] = f2bf(b.y); o.u[6] = f2bf(b.z); o.u[7] = f2bf(b.w);
    *(uint4*)(dst + i) = o.v;
}

// ---------------------------------------------------------------------------
// Tiled transpose + convert: src fp32 [R][Cc] -> dst bf16 [Cc][R]
// ---------------------------------------------------------------------------
__global__ void transpose_f32_bf16(const float* __restrict__ src,
                                   uint16_t* __restrict__ dst, int R, int Cc) {
    __shared__ uint16_t tile[32][33];
    int tx = threadIdx.x, ty = threadIdx.y;
    int c0 = blockIdx.x * 32, r0 = blockIdx.y * 32;
#pragma unroll
    for (int i = 0; i < 4; i++) {
        int r = ty + i * 8;
        tile[r][tx] = f2bf(src[(size_t)(r0 + r) * Cc + c0 + tx]);
    }
    __syncthreads();
#pragma unroll
    for (int i = 0; i < 4; i++) {
        int r = ty + i * 8;
        dst[(size_t)(c0 + r) * R + r0 + tx] = tile[tx][r];
    }
}

// ---------------------------------------------------------------------------
// m97-style GEMM, TM x 128 block tile (TM = 64 for both now).
// XOR-swizzled staging (conflict-free frag reads), LDS double-buffer.
// MODE 0: QKV epilogue — q row-major pre-scaled by 0.125*log2e; k,v
//   scattered to per-32-key-tile fragment order. MODE 1: bias + fp32 out.
// ---------------------------------------------------------------------------
template <int MODE, int TM>
__global__ __launch_bounds__(256) void gemm128(
    const uint16_t* __restrict__ A, const uint16_t* __restrict__ Bt,
    int Kdim, int Ncols,
    uint16_t* __restrict__ qws, uint16_t* __restrict__ kws,
    uint16_t* __restrict__ vtws,
    const float* __restrict__ bias, float* __restrict__ outp) {
    constexpr int MI = TM / 32;            // 16-row acc groups per wave
    __shared__ uint16_t lA[2][TM * 32];
    __shared__ uint16_t lB[2][4096];

    int tid = threadIdx.x;
    int w = tid >> 6, lane = tid & 63, quad = lane >> 4, lo = lane & 15;
    int mw = w >> 1, nw = w & 1;
    int m0 = blockIdx.y * TM;
    int n0 = blockIdx.x * 128;

    // staging: thread t -> LDS row t>>2 col (t&3); global chunk XOR-swizzled
    int srow = tid >> 2;
    int skc = ((tid & 3) ^ ((tid >> 3) & 3)) * 8;
    const uint16_t* gA0 = A + (size_t)(m0 + srow) * Kdim + skc;
    const uint16_t* gA1 = gA0 + (size_t)64 * Kdim;          // used if TM==128
    const uint16_t* gB0 = Bt + (size_t)(n0 + srow) * Kdim + skc;
    const uint16_t* gB1 = gB0 + (size_t)64 * Kdim;

    f32x4 acc[MI][4];
#pragma unroll
    for (int i = 0; i < MI; i++)
#pragma unroll
        for (int j = 0; j < 4; j++) acc[i][j] = (f32x4){0.f, 0.f, 0.f, 0.f};

    // reader base offsets (swizzled; i-invariant: 16/32-row steps keep
    // (row>>1)&3 == (lo>>1)&3)
    int swz = (quad ^ ((lo >> 1) & 3)) * 8;
    int aoff = (mw * (TM / 2) + lo) * 32 + swz;
    int boff = (nw * 64 + lo) * 32 + swz;

    const int nIter = Kdim >> 5;

    // preload tile 0 into buffer 0
    gload_lds16(gA0, &lA[0][tid * 8]);
    if (TM == 128) gload_lds16(gA1, &lA[0][2048 + tid * 8]);
    gload_lds16(gB0, &lB[0][tid * 8]);
    gload_lds16(gB1, &lB[0][2048 + tid * 8]);
    __syncthreads();

    for (int it = 0; it < nIter; it++) {
        const int cur = it & 1, nxt = cur ^ 1;
        const int kn = (it + 1 < nIter) ? (it + 1) * 32 : 0;  // last redundant

        gload_lds16(gA0 + kn, &lA[nxt][tid * 8]);
        if (TM == 128) gload_lds16(gA1 + kn, &lA[nxt][2048 + tid * 8]);
        gload_lds16(gB0 + kn, &lB[nxt][tid * 8]);
        gload_lds16(gB1 + kn, &lB[nxt][2048 + tid * 8]);

        bf16x8 af[MI], bfr[4];
#pragma unroll
        for (int i = 0; i < MI; i++) af[i] = *(const bf16x8*)(&lA[cur][aoff + i * 512]);
#pragma unroll
        for (int j = 0; j < 4; j++) bfr[j] = *(const bf16x8*)(&lB[cur][boff + j * 512]);
#pragma unroll
        for (int i = 0; i < MI; i++)
#pragma unroll
            for (int j = 0; j < 4; j++)
                acc[i][j] = __builtin_amdgcn_mfma_f32_16x16x32_bf16(
                    af[i], bfr[j], acc[i][j], 0, 0, 0);
        __syncthreads();  // drains prefetch (hidden by compute) + WAR on cur
    }

    if (MODE == 0) {
        int part = n0 / 768;
        int ccb = n0 % 768 + nw * 64;
        float qsc = (part == 0) ? 0.18033688011112042f : 1.0f;  // 0.125*log2(e)
#pragma unroll
        for (int i = 0; i < MI; i++)
#pragma unroll
            for (int j = 0; j < 4; j++)
#pragma unroll
                for (int r = 0; r < 4; r++) {
                    int m = m0 + mw * (TM / 2) + i * 16 + quad * 4 + r;
                    int bidx = m >> 10, nidx = m & 1023;
                    int cc = ccb + j * 16 + lo;
                    int h = cc >> 6, d = cc & 63;
                    int bh = bidx * 12 + h;
                    uint16_t v = f2bf(acc[i][j][r] * qsc);
                    int kt = nidx >> 5, keyin = nidx & 31;
                    if (part == 0) {
                        qws[((size_t)bh * 1024 + nidx) * 64 + d] = v;
                    } else if (part == 1) {
                        int fs = ((d >> 5) << 1) | (keyin & 1);
                        int idx = ((bh << 5) + kt) * 2048 + fs * 512 +
                                  ((((d & 31) >> 3) << 4) + (keyin >> 1)) * 8 + (d & 7);
                        kws[idx] = v;
                    } else {
                        int idx = ((bh << 5) + kt) * 2048 + (d >> 4) * 512 +
                                  (((keyin >> 3) << 4) + (d & 15)) * 8 + (keyin & 7);
                        vtws[idx] = v;
                    }
                }
    } else {
#pragma unroll
        for (int i = 0; i < MI; i++)
#pragma unroll
            for (int j = 0; j < 4; j++)
#pragma unroll
                for (int r = 0; r < 4; r++) {
                    int m = m0 + mw * (TM / 2) + i * 16 + quad * 4 + r;
                    int c = n0 + nw * 64 + j * 16 + lo;
                    outp[(size_t)m * Ncols + c] = acc[i][j][r] + bias[c];
                }
    }
}

// ---------------------------------------------------------------------------
// Flash attention (round 9 version, unchanged): chunked LDS staging — 2 K/V
// tiles (16 KB) per epoch, double-buffered, one barrier per epoch. grid
// (96 bh, 8 qt), block 256 = 4 waves x 32 q-rows. Fragment reads contiguous
// lane*16B. q pre-scaled (exp2 direct), perm-packed P, ones-MFMA row sums.
// ---------------------------------------------------------------------------
__global__ __launch_bounds__(256) void attn_kernel(
    const uint16_t* __restrict__ qws, const uint16_t* __restrict__ kws,
    const uint16_t* __restrict__ vtws, uint16_t* __restrict__ attnout) {
    int bh = blockIdx.x;
    int qt = blockIdx.y;
    int tid = threadIdx.x;
    int w = tid >> 6, lane = tid & 63, quad = lane >> 4, lo = lane & 15;
    int q0 = qt * 128 + w * 32;

    const uint16_t* Qb = qws + (size_t)bh * 65536;
    const uint16_t* Kt = kws + (size_t)bh * 65536;   // 32 tiles x 2048 u16
    const uint16_t* Vt = vtws + (size_t)bh * 65536;

    bf16x8 aq[2][2];
#pragma unroll
    for (int rg = 0; rg < 2; rg++)
#pragma unroll
        for (int h = 0; h < 2; h++)
            aq[rg][h] = *(const bf16x8*)(Qb + (size_t)(q0 + rg * 16 + lo) * 64 + h * 32 + quad * 8);

    f32x4 oacc[2][4], ol[2];
#pragma unroll
    for (int rg = 0; rg < 2; rg++) {
        ol[rg] = (f32x4){0.f, 0.f, 0.f, 0.f};
#pragma unroll
        for (int nd = 0; nd < 4; nd++) oacc[rg][nd] = (f32x4){0.f, 0.f, 0.f, 0.f};
    }

    bf16x8 ones;
#pragma unroll
    for (int i = 0; i < 8; i++) ones[i] = (__bf16)1.0f;

    __shared__ uint16_t Kbuf[2][4096];       // 2 x 8 KB (2 tiles/epoch)
    __shared__ uint16_t Vbuf[2][4096];       // 2 x 8 KB
    __shared__ uint16_t P[4][2][16][40];     // per-wave C->A staging (10 KB)

    const f32x4 zero4 = (f32x4){0.f, 0.f, 0.f, 0.f};

    // preload epoch 0 into buffer 0
    gload_lds16(Kt + tid * 8, &Kbuf[0][tid * 8]);
    gload_lds16(Kt + 2048 + tid * 8, &Kbuf[0][2048 + tid * 8]);
    gload_lds16(Vt + tid * 8, &Vbuf[0][tid * 8]);
    gload_lds16(Vt + 2048 + tid * 8, &Vbuf[0][2048 + tid * 8]);
    __syncthreads();

    for (int e = 0; e < 16; e++) {
        const int cur = e & 1, nxt = cur ^ 1;
        const int en = (e + 1) & 15;  // wrap: last prefetch redundant

        gload_lds16(Kt + en * 4096 + tid * 8, &Kbuf[nxt][tid * 8]);
        gload_lds16(Kt + en * 4096 + 2048 + tid * 8, &Kbuf[nxt][2048 + tid * 8]);
        gload_lds16(Vt + en * 4096 + tid * 8, &Vbuf[nxt][tid * 8]);
        gload_lds16(Vt + en * 4096 + 2048 + tid * 8, &Vbuf[nxt][2048 + tid * 8]);

#pragma unroll
        for (int tt = 0; tt < 2; tt++) {
            const uint16_t* Kb = &Kbuf[cur][tt * 2048];
            const uint16_t* Vb = &Vbuf[cur][tt * 2048];

            bf16x8 bk[2][2], vv[4];
#pragma unroll
            for (int t = 0; t < 2; t++)
#pragma unroll
                for (int h = 0; h < 2; h++)
                    bk[t][h] = *(const bf16x8*)(Kb + (h * 2 + t) * 512 + lane * 8);
#pragma unroll
            for (int nd = 0; nd < 4; nd++)
                vv[nd] = *(const bf16x8*)(Vb + nd * 512 + lane * 8);

#pragma unroll
            for (int rg = 0; rg < 2; rg++) {
                f32x4 s0 = __builtin_amdgcn_mfma_f32_16x16x32_bf16(aq[rg][0], bk[0][0], zero4, 0, 0, 0);
                s0 = __builtin_amdgcn_mfma_f32_16x16x32_bf16(aq[rg][1], bk[0][1], s0, 0, 0, 0);
                f32x4 s1 = __builtin_amdgcn_mfma_f32_16x16x32_bf16(aq[rg][0], bk[1][0], zero4, 0, 0, 0);
                s1 = __builtin_amdgcn_mfma_f32_16x16x32_bf16(aq[rg][1], bk[1][1], s1, 0, 0, 0);
#pragma unroll
                for (int r = 0; r < 4; r++) {
                    union { float f; unsigned u; } u0, u1;
                    u0.f = __builtin_exp2f(s0[r]);  // key 2*lo
                    u1.f = __builtin_exp2f(s1[r]);  // key 2*lo+1
                    unsigned pk = __builtin_amdgcn_perm(u1.u, u0.u, 0x07060302u);
                    *(unsigned*)&P[w][rg][quad * 4 + r][2 * lo] = pk;
                }
            }

#pragma unroll
            for (int rg = 0; rg < 2; rg++) {
                bf16x8 ap = *(const bf16x8*)(&P[w][rg][lo][quad * 8]);
                ol[rg] = __builtin_amdgcn_mfma_f32_16x16x32_bf16(ap, ones, ol[rg], 0, 0, 0);
#pragma unroll
                for (int nd = 0; nd < 4; nd++)
                    oacc[rg][nd] = __builtin_amdgcn_mfma_f32_16x16x32_bf16(ap, vv[nd], oacc[rg][nd], 0, 0, 0);
            }
        }
        __syncthreads();  // drains epoch prefetch (hidden by ~600 cyc compute)
    }

    int b = bh / 12, hh = bh % 12;
#pragma unroll
    for (int rg = 0; rg < 2; rg++)
#pragma unroll
        for (int r = 0; r < 4; r++) {
            float inv = 1.0f / ol[rg][r];
            int n = q0 + rg * 16 + quad * 4 + r;
            size_t base = ((size_t)(b * 1024 + n)) * 768 + hh * 64;
#pragma unroll
            for (int nd = 0; nd < 4; nd++)
                attnout[base + nd * 16 + lo] = f2bf(oacc[rg][nd][r] * inv);
        }
}

// ---------------------------------------------------------------------------
// Workspace layout (bytes):
//   xbf    @ 0          12,582,912
//   qws    @ 12582912   12,582,912
//   kws    @ 25165824   12,582,912   (tile-fragment order)
//   vtws   @ 37748736   12,582,912   (tile-fragment order)
//   attn   @ 50331648   12,582,912
//   wtqkv  @ 62914560    3,538,944
//   wtout  @ 66453504    1,179,648
// ---------------------------------------------------------------------------
extern "C" void kernel_launch(void* const* d_in, const int* in_sizes, int n_in,
                              void* d_out, int out_size, void* d_ws, size_t ws_size,
                              hipStream_t stream) {
    const float* x     = (const float*)d_in[0];
    const float* w_qkv = (const float*)d_in[1];
    const float* w_out = (const float*)d_in[2];
    const float* b_out = (const float*)d_in[3];
    float* out = (float*)d_out;

    char* ws = (char*)d_ws;
    uint16_t* xbf   = (uint16_t*)(ws);
    uint16_t* qws   = (uint16_t*)(ws + 12582912);
    uint16_t* kws   = (uint16_t*)(ws + 25165824);
    uint16_t* vtws  = (uint16_t*)(ws + 37748736);
    uint16_t* attn  = (uint16_t*)(ws + 50331648);
    uint16_t* wtqkv = (uint16_t*)(ws + 62914560);
    uint16_t* wtout = (uint16_t*)(ws + 66453504);

    cvt_f32_bf16<<<6291456 / 2048, 256, 0, stream>>>(x, xbf, 6291456);

    transpose_f32_bf16<<<dim3(2304 / 32, 768 / 32), dim3(32, 8), 0, stream>>>(w_qkv, wtqkv, 768, 2304);
    transpose_f32_bf16<<<dim3(768 / 32, 768 / 32), dim3(32, 8), 0, stream>>>(w_out, wtout, 768, 768);

    // QKV projection: [8192,768] @ [768,2304], 64x128 tiles (2304 blocks, 9/CU)
    gemm128<0, 64><<<dim3(18, 128), 256, 0, stream>>>(
        xbf, wtqkv, 768, 2304, qws, kws, vtws, nullptr, nullptr);

    attn_kernel<<<dim3(96, 8), 256, 0, stream>>>(qws, kws, vtws, attn);

    // out projection: [8192,768] @ [768,768] + bias, 64x128 tiles (768 blocks)
    gemm128<1, 64><<<dim3(6, 128), 256, 0, stream>>>(
        attn, wtout, 768, 768, nullptr, nullptr, nullptr, b_out, out);
}

// Round 11
// 212.931 us; speedup vs baseline: 1.0226x; 1.0226x over previous
//
#include <hip/hip_runtime.h>
#include <stdint.h>

// ---------------------------------------------------------------------------
// MHSA: B=8, N=1024, C=768, H=12, HD=64, SCALE=0.125
// Inputs/outputs fp32; internal compute bf16 MFMA with fp32 accumulation.
// Round 11: GEMM K-loop BK=32 -> BK=64 (12 barrier-drains instead of 24,
// ~380 cyc compute per drain vs ~190 — drain latency now mostly hidden).
// 64x128 tiles, XOR-swizzle, LDS dbuf (48 KB -> 3 blocks/CU). Attn unchanged.
// ---------------------------------------------------------------------------

typedef __attribute__((ext_vector_type(8))) __bf16 bf16x8;
typedef __attribute__((ext_vector_type(4))) float f32x4;

__device__ __forceinline__ uint16_t f2bf(float f) {
    union { float f; unsigned u; } c; c.f = f;
    unsigned x = c.u;
    unsigned r = (x + 0x7FFFu + ((x >> 16) & 1u)) >> 16;  // round-nearest-even
    return (uint16_t)r;
}

__device__ __forceinline__ void gload_lds16(const uint16_t* g, uint16_t* l) {
    __builtin_amdgcn_global_load_lds(
        (const __attribute__((address_space(1))) unsigned int*)g,
        (__attribute__((address_space(3))) unsigned int*)l, 16, 0, 0);
}

// ---------------------------------------------------------------------------
// fp32 -> bf16 convert, 8 elements/thread
// ---------------------------------------------------------------------------
__global__ __launch_bounds__(256) void cvt_f32_bf16(
    const float* __restrict__ src, uint16_t* __restrict__ dst, int n) {
    int i = (blockIdx.x * 256 + threadIdx.x) * 8;
    if (i + 8 > n) return;
    float4 a = *(const float4*)(src + i);
    float4 b = *(const float4*)(src + i + 4);
    union { uint16_t u[8]; uint4 v; } o;
    o.u[0] = f2bf(a.x); o.u[1] = f2bf(a.y); o.u[2] = f2bf(a.z); o.u[3] = f2bf(a.w);
    o.u[4] = f2bf(b.x); o.u[5] = f2bf(b.y); o.u[6] = f2bf(b.z); o.u[7] = f2bf(b.w);
    *(uint4*)(dst + i) = o.v;
}

// ---------------------------------------------------------------------------
// Tiled transpose + convert: src fp32 [R][Cc] -> dst bf16 [Cc][R]
// ---------------------------------------------------------------------------
__global__ void transpose_f32_bf16(const float* __restrict__ src,
                                   uint16_t* __restrict__ dst, int R, int Cc) {
    __shared__ uint16_t tile[32][33];
    int tx = threadIdx.x, ty = threadIdx.y;
    int c0 = blockIdx.x * 32, r0 = blockIdx.y * 32;
#pragma unroll
    for (int i = 0; i < 4; i++) {
        int r = ty + i * 8;
        tile[r][tx] = f2bf(src[(size_t)(r0 + r) * Cc + c0 + tx]);
    }
    __syncthreads();
#pragma unroll
    for (int i = 0; i < 4; i++) {
        int r = ty + i * 8;
        dst[(size_t)(c0 + r) * R + r0 + tx] = tile[tx][r];
    }
}

// ---------------------------------------------------------------------------
// GEMM 64x128 block tile, BK=64 (two 32-k sub-tiles per barrier).
// XOR-swizzled staging (conflict-free frag reads), LDS double-buffer.
// MODE 0: QKV epilogue — q row-major pre-scaled by 0.125*log2e; k,v
//   scattered to per-32-key-tile fragment order. MODE 1: bias + fp32 out.
// ---------------------------------------------------------------------------
template <int MODE>
__global__ __launch_bounds__(256) void gemm128(
    const uint16_t* __restrict__ A, const uint16_t* __restrict__ Bt,
    int Kdim, int Ncols,
    uint16_t* __restrict__ qws, uint16_t* __restrict__ kws,
    uint16_t* __restrict__ vtws,
    const float* __restrict__ bias, float* __restrict__ outp) {
    __shared__ uint16_t lA[2][2][2048];   // [buf][sub][64 rows x 32 k]
    __shared__ uint16_t lB[2][2][4096];   // [buf][sub][128 rows x 32 k]

    int tid = threadIdx.x;
    int w = tid >> 6, lane = tid & 63, quad = lane >> 4, lo = lane & 15;
    int mw = w >> 1, nw = w & 1;
    int m0 = blockIdx.y * 64;
    int n0 = blockIdx.x * 128;

    // staging: thread t -> LDS row t>>2 col (t&3); global chunk XOR-swizzled
    int srow = tid >> 2;
    int skc = ((tid & 3) ^ ((tid >> 3) & 3)) * 8;
    const uint16_t* gA0 = A + (size_t)(m0 + srow) * Kdim + skc;
    const uint16_t* gB0 = Bt + (size_t)(n0 + srow) * Kdim + skc;
    const uint16_t* gB1 = gB0 + (size_t)64 * Kdim;

    f32x4 acc[2][4];
#pragma unroll
    for (int i = 0; i < 2; i++)
#pragma unroll
        for (int j = 0; j < 4; j++) acc[i][j] = (f32x4){0.f, 0.f, 0.f, 0.f};

    // reader base offsets (swizzled; i-invariant: 16/32-row steps preserve
    // (row>>1)&3 == (lo>>1)&3)
    int swz = (quad ^ ((lo >> 1) & 3)) * 8;
    int aoff = (mw * 32 + lo) * 32 + swz;
    int boff = (nw * 64 + lo) * 32 + swz;

    const int nIter = Kdim >> 6;  // BK=64

    // preload k-tile 0 (both sub-tiles) into buffer 0
#pragma unroll
    for (int s = 0; s < 2; s++) {
        gload_lds16(gA0 + s * 32, &lA[0][s][tid * 8]);
        gload_lds16(gB0 + s * 32, &lB[0][s][tid * 8]);
        gload_lds16(gB1 + s * 32, &lB[0][s][2048 + tid * 8]);
    }
    __syncthreads();

    for (int it = 0; it < nIter; it++) {
        const int cur = it & 1, nxt = cur ^ 1;
        const int kn = (it + 1 < nIter) ? (it + 1) * 64 : 0;  // last redundant

        // prefetch next 64-k tile (drained at the barrier, ~380 cyc later)
#pragma unroll
        for (int s = 0; s < 2; s++) {
            gload_lds16(gA0 + kn + s * 32, &lA[nxt][s][tid * 8]);
            gload_lds16(gB0 + kn + s * 32, &lB[nxt][s][tid * 8]);
            gload_lds16(gB1 + kn + s * 32, &lB[nxt][s][2048 + tid * 8]);
        }

#pragma unroll
        for (int s = 0; s < 2; s++) {
            bf16x8 af[2], bfr[4];
#pragma unroll
            for (int i = 0; i < 2; i++) af[i] = *(const bf16x8*)(&lA[cur][s][aoff + i * 512]);
#pragma unroll
            for (int j = 0; j < 4; j++) bfr[j] = *(const bf16x8*)(&lB[cur][s][boff + j * 512]);
#pragma unroll
            for (int i = 0; i < 2; i++)
#pragma unroll
                for (int j = 0; j < 4; j++)
                    acc[i][j] = __builtin_amdgcn_mfma_f32_16x16x32_bf16(
                        af[i], bfr[j], acc[i][j], 0, 0, 0);
        }
        __syncthreads();  // drains prefetch (hidden by 16 MFMAs) + WAR on cur
    }

    if (MODE == 0) {
        int part = n0 / 768;
        int ccb = n0 % 768 + nw * 64;
        float qsc = (part == 0) ? 0.18033688011112042f : 1.0f;  // 0.125*log2(e)
#pragma unroll
        for (int i = 0; i < 2; i++)
#pragma unroll
            for (int j = 0; j < 4; j++)
#pragma unroll
                for (int r = 0; r < 4; r++) {
                    int m = m0 + mw * 32 + i * 16 + quad * 4 + r;
                    int bidx = m >> 10, nidx = m & 1023;
                    int cc = ccb + j * 16 + lo;
                    int h = cc >> 6, d = cc & 63;
                    int bh = bidx * 12 + h;
                    uint16_t v = f2bf(acc[i][j][r] * qsc);
                    int kt = nidx >> 5, keyin = nidx & 31;
                    if (part == 0) {
                        qws[((size_t)bh * 1024 + nidx) * 64 + d] = v;
                    } else if (part == 1) {
                        int fs = ((d >> 5) << 1) | (keyin & 1);
                        int idx = ((bh << 5) + kt) * 2048 + fs * 512 +
                                  ((((d & 31) >> 3) << 4) + (keyin >> 1)) * 8 + (d & 7);
                        kws[idx] = v;
                    } else {
                        int idx = ((bh << 5) + kt) * 2048 + (d >> 4) * 512 +
                                  (((keyin >> 3) << 4) + (d & 15)) * 8 + (keyin & 7);
                        vtws[idx] = v;
                    }
                }
    } else {
#pragma unroll
        for (int i = 0; i < 2; i++)
#pragma unroll
            for (int j = 0; j < 4; j++)
#pragma unroll
                for (int r = 0; r < 4; r++) {
                    int m = m0 + mw * 32 + i * 16 + quad * 4 + r;
                    int c = n0 + nw * 64 + j * 16 + lo;
                    outp[(size_t)m * Ncols + c] = acc[i][j][r] + bias[c];
                }
    }
}

// ---------------------------------------------------------------------------
// Flash attention (round 9 version, unchanged): chunked LDS staging — 2 K/V
// tiles (16 KB) per epoch, double-buffered, one barrier per epoch. grid
// (96 bh, 8 qt), block 256 = 4 waves x 32 q-rows. Fragment reads contiguous
// lane*16B. q pre-scaled (exp2 direct), perm-packed P, ones-MFMA row sums.
// ---------------------------------------------------------------------------
__global__ __launch_bounds__(256) void attn_kernel(
    const uint16_t* __restrict__ qws, const uint16_t* __restrict__ kws,
    const uint16_t* __restrict__ vtws, uint16_t* __restrict__ attnout) {
    int bh = blockIdx.x;
    int qt = blockIdx.y;
    int tid = threadIdx.x;
    int w = tid >> 6, lane = tid & 63, quad = lane >> 4, lo = lane & 15;
    int q0 = qt * 128 + w * 32;

    const uint16_t* Qb = qws + (size_t)bh * 65536;
    const uint16_t* Kt = kws + (size_t)bh * 65536;   // 32 tiles x 2048 u16
    const uint16_t* Vt = vtws + (size_t)bh * 65536;

    bf16x8 aq[2][2];
#pragma unroll
    for (int rg = 0; rg < 2; rg++)
#pragma unroll
        for (int h = 0; h < 2; h++)
            aq[rg][h] = *(const bf16x8*)(Qb + (size_t)(q0 + rg * 16 + lo) * 64 + h * 32 + quad * 8);

    f32x4 oacc[2][4], ol[2];
#pragma unroll
    for (int rg = 0; rg < 2; rg++) {
        ol[rg] = (f32x4){0.f, 0.f, 0.f, 0.f};
#pragma unroll
        for (int nd = 0; nd < 4; nd++) oacc[rg][nd] = (f32x4){0.f, 0.f, 0.f, 0.f};
    }

    bf16x8 ones;
#pragma unroll
    for (int i = 0; i < 8; i++) ones[i] = (__bf16)1.0f;

    __shared__ uint16_t Kbuf[2][4096];       // 2 x 8 KB (2 tiles/epoch)
    __shared__ uint16_t Vbuf[2][4096];       // 2 x 8 KB
    __shared__ uint16_t P[4][2][16][40];     // per-wave C->A staging (10 KB)

    const f32x4 zero4 = (f32x4){0.f, 0.f, 0.f, 0.f};

    // preload epoch 0 into buffer 0
    gload_lds16(Kt + tid * 8, &Kbuf[0][tid * 8]);
    gload_lds16(Kt + 2048 + tid * 8, &Kbuf[0][2048 + tid * 8]);
    gload_lds16(Vt + tid * 8, &Vbuf[0][tid * 8]);
    gload_lds16(Vt + 2048 + tid * 8, &Vbuf[0][2048 + tid * 8]);
    __syncthreads();

    for (int e = 0; e < 16; e++) {
        const int cur = e & 1, nxt = cur ^ 1;
        const int en = (e + 1) & 15;  // wrap: last prefetch redundant

        gload_lds16(Kt + en * 4096 + tid * 8, &Kbuf[nxt][tid * 8]);
        gload_lds16(Kt + en * 4096 + 2048 + tid * 8, &Kbuf[nxt][2048 + tid * 8]);
        gload_lds16(Vt + en * 4096 + tid * 8, &Vbuf[nxt][tid * 8]);
        gload_lds16(Vt + en * 4096 + 2048 + tid * 8, &Vbuf[nxt][2048 + tid * 8]);

#pragma unroll
        for (int tt = 0; tt < 2; tt++) {
            const uint16_t* Kb = &Kbuf[cur][tt * 2048];
            const uint16_t* Vb = &Vbuf[cur][tt * 2048];

            bf16x8 bk[2][2], vv[4];
#pragma unroll
            for (int t = 0; t < 2; t++)
#pragma unroll
                for (int h = 0; h < 2; h++)
                    bk[t][h] = *(const bf16x8*)(Kb + (h * 2 + t) * 512 + lane * 8);
#pragma unroll
            for (int nd = 0; nd < 4; nd++)
                vv[nd] = *(const bf16x8*)(Vb + nd * 512 + lane * 8);

#pragma unroll
            for (int rg = 0; rg < 2; rg++) {
                f32x4 s0 = __builtin_amdgcn_mfma_f32_16x16x32_bf16(aq[rg][0], bk[0][0], zero4, 0, 0, 0);
                s0 = __builtin_amdgcn_mfma_f32_16x16x32_bf16(aq[rg][1], bk[0][1], s0, 0, 0, 0);
                f32x4 s1 = __builtin_amdgcn_mfma_f32_16x16x32_bf16(aq[rg][0], bk[1][0], zero4, 0, 0, 0);
                s1 = __builtin_amdgcn_mfma_f32_16x16x32_bf16(aq[rg][1], bk[1][1], s1, 0, 0, 0);
#pragma unroll
                for (int r = 0; r < 4; r++) {
                    union { float f; unsigned u; } u0, u1;
                    u0.f = __builtin_exp2f(s0[r]);  // key 2*lo
                    u1.f = __builtin_exp2f(s1[r]);  // key 2*lo+1
                    unsigned pk = __builtin_amdgcn_perm(u1.u, u0.u, 0x07060302u);
                    *(unsigned*)&P[w][rg][quad * 4 + r][2 * lo] = pk;
                }
            }

#pragma unroll
            for (int rg = 0; rg < 2; rg++) {
                bf16x8 ap = *(const bf16x8*)(&P[w][rg][lo][quad * 8]);
                ol[rg] = __builtin_amdgcn_mfma_f32_16x16x32_bf16(ap, ones, ol[rg], 0, 0, 0);
#pragma unroll
                for (int nd = 0; nd < 4; nd++)
                    oacc[rg][nd] = __builtin_amdgcn_mfma_f32_16x16x32_bf16(ap, vv[nd], oacc[rg][nd], 0, 0, 0);
            }
        }
        __syncthreads();  // drains epoch prefetch (hidden by ~600 cyc compute)
    }

    int b = bh / 12, hh = bh % 12;
#pragma unroll
    for (int rg = 0; rg < 2; rg++)
#pragma unroll
        for (int r = 0; r < 4; r++) {
            float inv = 1.0f / ol[rg][r];
            int n = q0 + rg * 16 + quad * 4 + r;
            size_t base = ((size_t)(b * 1024 + n)) * 768 + hh * 64;
#pragma unroll
            for (int nd = 0; nd < 4; nd++)
                attnout[base + nd * 16 + lo] = f2bf(oacc[rg][nd][r] * inv);
        }
}

// ---------------------------------------------------------------------------
// Workspace layout (bytes):
//   xbf    @ 0          12,582,912
//   qws    @ 12582912   12,582,912
//   kws    @ 25165824   12,582,912   (tile-fragment order)
//   vtws   @ 37748736   12,582,912   (tile-fragment order)
//   attn   @ 50331648   12,582,912
//   wtqkv  @ 62914560    3,538,944
//   wtout  @ 66453504    1,179,648
// ---------------------------------------------------------------------------
extern "C" void kernel_launch(void* const* d_in, const int* in_sizes, int n_in,
                              void* d_out, int out_size, void* d_ws, size_t ws_size,
                              hipStream_t stream) {
    const float* x     = (const float*)d_in[0];
    const float* w_qkv = (const float*)d_in[1];
    const float* w_out = (const float*)d_in[2];
    const float* b_out = (const float*)d_in[3];
    float* out = (float*)d_out;

    char* ws = (char*)d_ws;
    uint16_t* xbf   = (uint16_t*)(ws);
    uint16_t* qws   = (uint16_t*)(ws + 12582912);
    uint16_t* kws   = (uint16_t*)(ws + 25165824);
    uint16_t* vtws  = (uint16_t*)(ws + 37748736);
    uint16_t* attn  = (uint16_t*)(ws + 50331648);
    uint16_t* wtqkv = (uint16_t*)(ws + 62914560);
    uint16_t* wtout = (uint16_t*)(ws + 66453504);

    cvt_f32_bf16<<<6291456 / 2048, 256, 0, stream>>>(x, xbf, 6291456);

    transpose_f32_bf16<<<dim3(2304 / 32, 768 / 32), dim3(32, 8), 0, stream>>>(w_qkv, wtqkv, 768, 2304);
    transpose_f32_bf16<<<dim3(768 / 32, 768 / 32), dim3(32, 8), 0, stream>>>(w_out, wtout, 768, 768);

    // QKV projection: [8192,768] @ [768,2304], 64x128 tiles (2304 blocks)
    gemm128<0><<<dim3(18, 128), 256, 0, stream>>>(
        xbf, wtqkv, 768, 2304, qws, kws, vtws, nullptr, nullptr);

    attn_kernel<<<dim3(96, 8), 256, 0, stream>>>(qws, kws, vtws, attn);

    // out projection: [8192,768] @ [768,768] + bias, 64x128 tiles (768 blocks)
    gemm128<1><<<dim3(6, 128), 256, 0, stream>>>(
        attn, wtout, 768, 768, nullptr, nullptr, nullptr, b_out, out);
}